// Round 21
// baseline (486.860 us; speedup 1.0000x reference)
//
#include <hip/hip_runtime.h>
#include <math.h>

#define NB 32
#define HW 4096
#define NS 16
#define EDIM 256
#define FFND 1024
#define EPS_LN 1e-5f
#define EPS_ATTN 1e-5f
#define BPB 32            // sub-blocks per batch in bigpass
#define RPB 128           // rows per bigpass block (HW/BPB)
#define TROWS 16          // rows per barrier-tile

__device__ __forceinline__ float sigmoidf_(float x) { return 1.0f / (1.0f + __expf(-x)); }
__device__ __forceinline__ float gelu_(float x) {
    float x3 = x * x * x;
    return 0.5f * x * (1.0f + tanhf(0.7978845608028654f * (x + 0.044715f * x3)));
}

// Sum across the 16-lane DPP row via row_ror rotations — pure VALU pipe.
__device__ __forceinline__ float rsum16(float v) {
    int x;
    x = __builtin_amdgcn_update_dpp(0, __float_as_int(v), 0x128, 0xF, 0xF, true); // ror:8
    v += __int_as_float(x);
    x = __builtin_amdgcn_update_dpp(0, __float_as_int(v), 0x124, 0xF, 0xF, true); // ror:4
    v += __int_as_float(x);
    x = __builtin_amdgcn_update_dpp(0, __float_as_int(v), 0x122, 0xF, 0xF, true); // ror:2
    v += __int_as_float(x);
    x = __builtin_amdgcn_update_dpp(0, __float_as_int(v), 0x121, 0xF, 0xF, true); // ror:1
    v += __int_as_float(x);
    return v;
}
// Max across the 16-lane DPP row.
__device__ __forceinline__ float rmax16(float v) {
    int x;
    x = __builtin_amdgcn_update_dpp(0, __float_as_int(v), 0x128, 0xF, 0xF, true);
    v = fmaxf(v, __int_as_float(x));
    x = __builtin_amdgcn_update_dpp(0, __float_as_int(v), 0x124, 0xF, 0xF, true);
    v = fmaxf(v, __int_as_float(x));
    x = __builtin_amdgcn_update_dpp(0, __float_as_int(v), 0x122, 0xF, 0xF, true);
    v = fmaxf(v, __int_as_float(x));
    x = __builtin_amdgcn_update_dpp(0, __float_as_int(v), 0x121, 0xF, 0xF, true);
    v = fmaxf(v, __int_as_float(x));
    return v;
}

// W[j][c] = scale * sum_e w_q[e][j] * w_k[e][c]   (scale = 256^-0.5 = 1/16)
__global__ __launch_bounds__(256) void k_prep(const float* __restrict__ w_q,
                                              const float* __restrict__ w_k,
                                              float* __restrict__ W) {
    const int j = blockIdx.x;
    const int c = threadIdx.x;
    __shared__ float colq[EDIM];
    colq[c] = w_q[(size_t)c * EDIM + j];
    __syncthreads();
    float acc = 0.f;
#pragma unroll 4
    for (int e = 0; e < EDIM; ++e)
        acc += colq[e] * w_k[e * EDIM + c];
    W[j * EDIM + c] = acc * 0.0625f;
}

// M[e][o] = sum_c w_v[c][e] * w_ih[o][c]  — folds w_v into w_ih so the chain
// computes gi = ub @ M directly (k_upd's GEMV deleted). Reads w_ihT coalesced.
// grid 256 (e), 256 threads, 3 chunks of o.
__global__ __launch_bounds__(256) void k_prepM(
    const float* __restrict__ w_v, const float* __restrict__ w_ihT,
    float* __restrict__ M) {
    const int e = blockIdx.x;
    const int t = threadIdx.x;
    __shared__ float colv[EDIM];
    colv[t] = w_v[(size_t)t * EDIM + e];
    __syncthreads();
#pragma unroll 1
    for (int k = 0; k < 3; ++k) {
        const int o = k * 256 + t;
        float acc = 0.f;
#pragma unroll 4
        for (int c = 0; c < EDIM; ++c)
            acc += colv[c] * w_ihT[(size_t)c * 768 + o];
        M[(size_t)e * 768 + o] = acc;
    }
}

// Batched tiled transpose of 4 weight matrices in ONE launch (224 blocks).
// blocks 0..47: w_ih(768x256); 48..95: w_hh(768x256); 96..159: w_f1(1024x256);
// 160..223: w_f2(256x1024).   (w_v transpose no longer needed — folded into M.)
__global__ __launch_bounds__(256) void k_tr_all(
    const float* __restrict__ w_ih, const float* __restrict__ w_hh,
    const float* __restrict__ w_f1, const float* __restrict__ w_f2,
    float* __restrict__ w_ihT, float* __restrict__ w_hhT,
    float* __restrict__ w_f1T, float* __restrict__ w_f2T) {
    __shared__ float tile[64][65];
    const int bid = blockIdx.x;
    const float* src; float* dst; int R, C, lb;
    if (bid < 48)       { src = w_ih; dst = w_ihT; R = 768;  C = 256;  lb = bid; }
    else if (bid < 96)  { src = w_hh; dst = w_hhT; R = 768;  C = 256;  lb = bid - 48; }
    else if (bid < 160) { src = w_f1; dst = w_f1T; R = 1024; C = 256;  lb = bid - 96; }
    else                { src = w_f2; dst = w_f2T; R = 256;  C = 1024; lb = bid - 160; }
    const int tilesC = C >> 6;
    const int tR = (lb / tilesC) << 6;
    const int tC = (lb % tilesC) << 6;
    const int t = threadIdx.x;
    {
        const int r = t >> 2;
        const int c0 = (t & 3) << 4;
#pragma unroll
        for (int i = 0; i < 16; i += 4) {
            const float4 v = *reinterpret_cast<const float4*>(src + (size_t)(tR + r) * C + tC + c0 + i);
            tile[r][c0 + i] = v.x; tile[r][c0 + i + 1] = v.y;
            tile[r][c0 + i + 2] = v.z; tile[r][c0 + i + 3] = v.w;
        }
    }
    __syncthreads();
    {
        const int c = t >> 2;
        const int r0 = (t & 3) << 4;
#pragma unroll
        for (int i = 0; i < 16; ++i)
            dst[(size_t)(tC + c) * R + tR + r0 + i] = tile[r0 + i][c];
    }
}

// Iteration-0 only: qn = LN(query_row); qpk = qn @ W; gq/bq scalars.
__global__ void k_qproj(const float* __restrict__ qsrc, const float* __restrict__ g_q,
                        const float* __restrict__ b_q, const float* __restrict__ W,
                        const float* __restrict__ g_kv, const float* __restrict__ b_kv,
                        float* __restrict__ qpk, float* __restrict__ gqbq) {
    const int row = blockIdx.x;   // 0..511  (= b*16 + s)
    const int t = threadIdx.x;
    __shared__ float qn[EDIM];
    __shared__ float red[16];
    const float v = qsrc[(size_t)row * EDIM + t];
    float s = v, ss = v * v;
#pragma unroll
    for (int m = 1; m < 64; m <<= 1) { s += __shfl_xor(s, m); ss += __shfl_xor(ss, m); }
    const int wave = t >> 6, lane = t & 63;
    if (lane == 0) { red[wave] = s; red[8 + wave] = ss; }
    __syncthreads();
    const float st = red[0] + red[1] + red[2] + red[3];
    const float sst = red[8] + red[9] + red[10] + red[11];
    const float mean = st * (1.0f / EDIM);
    const float rstd = rsqrtf(sst * (1.0f / EDIM) - mean * mean + EPS_LN);
    qn[t] = (v - mean) * rstd * g_q[t] + b_q[t];
    __syncthreads();
    float acc = 0.f;
#pragma unroll 4
    for (int j = 0; j < EDIM; ++j)
        acc += qn[j] * W[j * EDIM + t];
    qpk[(size_t)row * EDIM + t] = acc;
    float u = acc * g_kv[t];
    float w2 = acc * b_kv[t];
#pragma unroll
    for (int m = 1; m < 64; m <<= 1) { u += __shfl_xor(u, m); w2 += __shfl_xor(w2, m); }
    __syncthreads();
    if (lane == 0) { red[wave] = u; red[8 + wave] = w2; }
    __syncthreads();
    if (t == 0) {
        const int b = row >> 4, sl = row & 15;
        gqbq[b * 32 + sl] = red[0] + red[1] + red[2] + red[3];
        gqbq[b * 32 + 16 + sl] = red[8] + red[9] + red[10] + red[11];
    }
}

// Streaming pass v10 (proven 84us): G in regs, slot-split dot, DPP reductions,
// TROWS=16, register prefetch of next tile.
template <bool LAST>
__global__ __launch_bounds__(256, 2) void k_bigpass(
    const float* __restrict__ input, const float* __restrict__ qpk,
    const float* __restrict__ gqbq, const float* __restrict__ g_kv,
    float* __restrict__ pacc, float* __restrict__ psum, float* __restrict__ attn_out) {
    const int b = blockIdx.x >> 5;        // /BPB
    const int sub = blockIdx.x & 31;      // %BPB
    const int t = threadIdx.x;
    const int w = t >> 6;
    const int lane = t & 63;
    const int gp = (t >> 4) & 3;
    const int g = t >> 4;
    const int j = t & 15;

    __shared__ __align__(16) float stage[TROWS][264];
    __shared__ __align__(16) float wrec[TROWS][20];
    __shared__ __align__(16) float logit_lds[TROWS][NS];

    const float gqj = gqbq[b * 32 + j];
    const float bqj = gqbq[b * 32 + 16 + j];

    float4 Greg[4][4];
#pragma unroll
    for (int sp = 0; sp < 4; ++sp) {
#pragma unroll
        for (int c = 0; c < 4; ++c) {
            const int off = (c * 16 + j) * 4;
            const float4 qv = *reinterpret_cast<const float4*>(
                qpk + (size_t)b * 4096 + (w * 4 + sp) * 256 + off);
            const float4 gv = *reinterpret_cast<const float4*>(g_kv + off);
            Greg[sp][c] = make_float4(qv.x * gv.x, qv.y * gv.y, qv.z * gv.z, qv.w * gv.w);
        }
    }

    float acc[4][4];
    float S[4], A[4];
#pragma unroll
    for (int si = 0; si < 4; ++si) {
        acc[si][0] = acc[si][1] = acc[si][2] = acc[si][3] = 0.f;
        S[si] = 0.f; A[si] = 0.f;
    }

    const int rowbase = sub * RPB;

    float4 xh[4];
    {
        const float* xa = input + ((size_t)b * HW + rowbase + g) * EDIM;
#pragma unroll
        for (int c = 0; c < 4; ++c)
            xh[c] = *reinterpret_cast<const float4*>(xa + (c * 16 + j) * 4);
    }

#pragma unroll 1
    for (int tt = 0; tt < RPB / TROWS; ++tt) {
        const int grow = rowbase + tt * TROWS + g;

        float s1 = 0.f, s2 = 0.f;
#pragma unroll
        for (int c = 0; c < 4; ++c) {
            const int off = (c * 16 + j) * 4;
            *reinterpret_cast<float4*>(&stage[g][off]) = xh[c];
            s1 += xh[c].x + xh[c].y + xh[c].z + xh[c].w;
            s2 += xh[c].x * xh[c].x + xh[c].y * xh[c].y + xh[c].z * xh[c].z + xh[c].w * xh[c].w;
        }
        s1 = rsum16(s1);
        s2 = rsum16(s2);
        const float mean = s1 * (1.0f / EDIM);
        const float rstd = rsqrtf(s2 * (1.0f / EDIM) - mean * mean + EPS_LN);
        __syncthreads();

        if (tt + 1 < RPB / TROWS) {
            const float* xn = input + ((size_t)b * HW + rowbase + (tt + 1) * TROWS + g) * EDIM;
#pragma unroll
            for (int c = 0; c < 4; ++c)
                xh[c] = *reinterpret_cast<const float4*>(xn + (c * 16 + j) * 4);
        }

#pragma unroll
        for (int rb = 0; rb < 4; ++rb) {
            const int row = rb * 4 + gp;
            float d0 = 0.f, d1 = 0.f, d2 = 0.f, d3 = 0.f;
#pragma unroll
            for (int c = 0; c < 4; ++c) {
                const int off = (c * 16 + j) * 4;
                const float4 x = *reinterpret_cast<const float4*>(&stage[row][off]);
                d0 += x.x * Greg[0][c].x + x.y * Greg[0][c].y + x.z * Greg[0][c].z + x.w * Greg[0][c].w;
                d1 += x.x * Greg[1][c].x + x.y * Greg[1][c].y + x.z * Greg[1][c].z + x.w * Greg[1][c].w;
                d2 += x.x * Greg[2][c].x + x.y * Greg[2][c].y + x.z * Greg[2][c].z + x.w * Greg[2][c].w;
                d3 += x.x * Greg[3][c].x + x.y * Greg[3][c].y + x.z * Greg[3][c].z + x.w * Greg[3][c].w;
            }
            d0 = rsum16(d0); d1 = rsum16(d1); d2 = rsum16(d2); d3 = rsum16(d3);
            if (j == 0)
                *reinterpret_cast<float4*>(&logit_lds[row][w * 4]) =
                    make_float4(d0, d1, d2, d3);
        }
        __syncthreads();

        {
            float L = logit_lds[g][j];
            L = rstd * (L - mean * gqj) + bqj;
            const float mx = rmax16(L);
            const float p = __expf(L - mx);
            const float tot = rsum16(p);
            const float at = p / tot;
            wrec[g][j] = at;
            if (j == 0) {
                wrec[g][16] = rstd;
                wrec[g][17] = rstd * mean;
            }
            if (LAST)
                attn_out[((size_t)(b * NS + j)) * HW + grow] = at;
        }
        __syncthreads();

        {
            const int ch = lane * 4;
            const int sbase = w * 4;
#pragma unroll
            for (int r = 0; r < TROWS; ++r) {
                const float4 xv = *reinterpret_cast<const float4*>(&stage[r][ch]);
                const float4 at = *reinterpret_cast<const float4*>(&wrec[r][sbase]);
                const float rr = wrec[r][16];
                const float rm = wrec[r][17];
                float wg;
                wg = at.x * rr;
                acc[0][0] += wg * xv.x; acc[0][1] += wg * xv.y;
                acc[0][2] += wg * xv.z; acc[0][3] += wg * xv.w;
                S[0] += at.x; A[0] += at.x * rm;
                wg = at.y * rr;
                acc[1][0] += wg * xv.x; acc[1][1] += wg * xv.y;
                acc[1][2] += wg * xv.z; acc[1][3] += wg * xv.w;
                S[1] += at.y; A[1] += at.y * rm;
                wg = at.z * rr;
                acc[2][0] += wg * xv.x; acc[2][1] += wg * xv.y;
                acc[2][2] += wg * xv.z; acc[2][3] += wg * xv.w;
                S[2] += at.z; A[2] += at.z * rm;
                wg = at.w * rr;
                acc[3][0] += wg * xv.x; acc[3][1] += wg * xv.y;
                acc[3][2] += wg * xv.z; acc[3][3] += wg * xv.w;
                S[3] += at.w; A[3] += at.w * rm;
            }
        }
        __syncthreads();
    }

#pragma unroll
    for (int si = 0; si < 4; ++si) {
        *reinterpret_cast<float4*>(
            pacc + ((size_t)blockIdx.x * NS + w * 4 + si) * EDIM + lane * 4) =
            make_float4(acc[si][0], acc[si][1], acc[si][2], acc[si][3]);
    }
    if (lane == 0) {
#pragma unroll
        for (int si = 0; si < 4; ++si) {
            psum[blockIdx.x * 32 + w * 4 + si] = S[si];
            psum[blockIdx.x * 32 + 16 + w * 4 + si] = A[si];
        }
    }
}

// k_ub: reduce partials + normalize -> ub only (GEMV folded into M/k_gates).
// grid 512 (1 row/block).
__global__ __launch_bounds__(256) void k_ub(
    const float* __restrict__ pacc, const float* __restrict__ psum,
    const float* __restrict__ g_kv, const float* __restrict__ b_kv,
    float* __restrict__ ub) {
    const int row = blockIdx.x;          // 0..511
    const int b = row >> 4;
    const int s = row & 15;
    const int t = threadIdx.x;
    __shared__ float sSA[2];
    if (t < 2) {
        float v = 0.f;
        for (int p = 0; p < BPB; ++p)
            v += psum[(b * BPB + p) * 32 + t * 16 + s];
        sSA[t] = v;
    }
    float V = 0.f;
    for (int p = 0; p < BPB; ++p)
        V += pacc[((size_t)(b * BPB + p) * NS + s) * EDIM + t];
    __syncthreads();
    const float Sv = sSA[0], Av = sSA[1];
    ub[(size_t)row * EDIM + t] = (g_kv[t] * (V - Av) + b_kv[t] * Sv) / (Sv + EPS_ATTN);
}

// G2a v3: 2 rows/block (grid 1536). ih blocks read ub with folded weight M;
// hh blocks read qprev with w_hhT. Structure unchanged.
__global__ __launch_bounds__(256) void k_gates(
    const float* __restrict__ ub, const float* __restrict__ qprev,
    const float* __restrict__ M, const float* __restrict__ w_hhT,
    const float* __restrict__ b_ih, const float* __restrict__ b_hh,
    float* __restrict__ gig) {
    const int rt = blockIdx.x / 6;
    const int ct = blockIdx.x % 6;
    const int row0 = rt * 2;
    const int t = threadIdx.x;
    const bool ih = ct < 3;
    const int lc = (ih ? ct : ct - 3) * 256 + t;
    const float* __restrict__ src = ih ? ub : qprev;
    const float* __restrict__ wT = ih ? M : w_hhT;

    __shared__ __align__(16) float in2[2][EDIM];
#pragma unroll
    for (int r = 0; r < 2; ++r)
        in2[r][t] = src[(size_t)(row0 + r) * EDIM + t];
    __syncthreads();

    float a0 = 0.f, a1 = 0.f;
#pragma unroll 4
    for (int j = 0; j < EDIM; j += 4) {
        const float4 x0 = *reinterpret_cast<const float4*>(&in2[0][j]);
        const float4 x1 = *reinterpret_cast<const float4*>(&in2[1][j]);
        const float w0 = wT[(size_t)j * 768 + lc];
        const float w1 = wT[(size_t)(j + 1) * 768 + lc];
        const float w2 = wT[(size_t)(j + 2) * 768 + lc];
        const float w3 = wT[(size_t)(j + 3) * 768 + lc];
        a0 += x0.x * w0 + x0.y * w1 + x0.z * w2 + x0.w * w3;
        a1 += x1.x * w0 + x1.y * w1 + x1.z * w2 + x1.w * w3;
    }
    const float bias = ih ? b_ih[lc] : b_hh[lc];
    const int gcol = ih ? lc : 768 + lc;
    gig[(size_t)(row0 + 0) * 1536 + gcol] = a0 + bias;
    gig[(size_t)(row0 + 1) * 1536 + gcol] = a1 + bias;
}

// G2b+G3 v2: 2 rows/block (grid 1024): GRU + LN + ffn1 slice.
__global__ __launch_bounds__(256) void k_gruffn1(
    const float* __restrict__ gig, const float* __restrict__ qprev,
    const float* __restrict__ g_2, const float* __restrict__ b_2,
    const float* __restrict__ w_f1T, const float* __restrict__ b_f1,
    float* __restrict__ slots, float* __restrict__ h1) {
    const int rt = blockIdx.x >> 2;
    const int ct = blockIdx.x & 3;
    const int row0 = rt * 2;
    const int t = threadIdx.x;
    const int wave = t >> 6, lane = t & 63;
    __shared__ __align__(16) float ln2[2][EDIM];
    __shared__ float red[4][4];

    float sl[2];
#pragma unroll
    for (int r = 0; r < 2; ++r) {
        const size_t base = (size_t)(row0 + r) * 1536;
        const float ir = gig[base + t];
        const float iz = gig[base + 256 + t];
        const float inn = gig[base + 512 + t];
        const float hr = gig[base + 768 + t];
        const float hz = gig[base + 1024 + t];
        const float hn = gig[base + 1280 + t];
        const float h = qprev[(size_t)(row0 + r) * EDIM + t];
        const float rg = sigmoidf_(ir + hr);
        const float z = sigmoidf_(iz + hz);
        const float n = tanhf(inn + rg * hn);
        sl[r] = (1.0f - z) * n + z * h;
    }
    if (ct == 0) {
#pragma unroll
        for (int r = 0; r < 2; ++r)
            slots[(size_t)(row0 + r) * EDIM + t] = sl[r];
    }
    {
        float a[2], qq[2];
#pragma unroll
        for (int r = 0; r < 2; ++r) { a[r] = sl[r]; qq[r] = sl[r] * sl[r]; }
#pragma unroll
        for (int m = 1; m < 64; m <<= 1) {
#pragma unroll
            for (int r = 0; r < 2; ++r) {
                a[r] += __shfl_xor(a[r], m);
                qq[r] += __shfl_xor(qq[r], m);
            }
        }
        if (lane == 0) {
#pragma unroll
            for (int r = 0; r < 2; ++r) { red[wave][r] = a[r]; red[wave][2 + r] = qq[r]; }
        }
    }
    __syncthreads();
    {
        const float g = g_2[t], bb = b_2[t];
#pragma unroll
        for (int r = 0; r < 2; ++r) {
            const float Sv = red[0][r] + red[1][r] + red[2][r] + red[3][r];
            const float Qv = red[0][2 + r] + red[1][2 + r] + red[2][2 + r] + red[3][2 + r];
            const float mn = Sv * (1.0f / EDIM);
            const float rs = rsqrtf(Qv * (1.0f / EDIM) - mn * mn + EPS_LN);
            ln2[r][t] = (sl[r] - mn) * rs * g + bb;
        }
    }
    __syncthreads();

    const int c = ct * 256 + t;
    float a0 = 0.f, a1 = 0.f;
#pragma unroll 4
    for (int j = 0; j < EDIM; j += 4) {
        const float4 x0 = *reinterpret_cast<const float4*>(&ln2[0][j]);
        const float4 x1 = *reinterpret_cast<const float4*>(&ln2[1][j]);
        const float w0 = w_f1T[(size_t)j * FFND + c];
        const float w1 = w_f1T[(size_t)(j + 1) * FFND + c];
        const float w2 = w_f1T[(size_t)(j + 2) * FFND + c];
        const float w3 = w_f1T[(size_t)(j + 3) * FFND + c];
        a0 += x0.x * w0 + x0.y * w1 + x0.z * w2 + x0.w * w3;
        a1 += x1.x * w0 + x1.y * w1 + x1.z * w2 + x1.w * w3;
    }
    const float bf = b_f1[c];
    h1[(size_t)(row0 + 0) * FFND + c] = gelu_(a0 + bf);
    h1[(size_t)(row0 + 1) * FFND + c] = gelu_(a1 + bf);
}

// G4+G5 v2: 1 row/block (grid 512).
__global__ __launch_bounds__(256) void k_ffn2qpk(
    const float* __restrict__ h1, const float* __restrict__ slots,
    const float* __restrict__ w_f2T, const float* __restrict__ b_f2,
    const float* __restrict__ query,
    const float* __restrict__ g_q, const float* __restrict__ b_q,
    const float* __restrict__ W,
    const float* __restrict__ g_kv, const float* __restrict__ b_kv,
    float* __restrict__ q_out, float* __restrict__ qpk, float* __restrict__ gqbq,
    int adjust, int do_qpk) {
    const int row = blockIdx.x;
    const int t = threadIdx.x;
    const int wave = t >> 6, lane = t & 63;
    __shared__ __align__(16) float in1[FFND];
    __shared__ float red[4][2];
    __shared__ __align__(16) float qn[EDIM];

    *reinterpret_cast<float4*>(&in1[t * 4]) =
        *reinterpret_cast<const float4*>(h1 + (size_t)row * FFND + t * 4);
    __syncthreads();
    float a0 = 0.f;
#pragma unroll 4
    for (int j = 0; j < FFND; j += 4) {
        const float4 x0 = *reinterpret_cast<const float4*>(&in1[j]);
        a0 += x0.x * w_f2T[(size_t)j * EDIM + t] + x0.y * w_f2T[(size_t)(j + 1) * EDIM + t]
            + x0.z * w_f2T[(size_t)(j + 2) * EDIM + t] + x0.w * w_f2T[(size_t)(j + 3) * EDIM + t];
    }
    float v0 = slots[(size_t)row * EDIM + t] + a0 + b_f2[t];
    if (adjust) {
        const float qq0 = query[(size_t)row * EDIM + t];
        v0 = (v0 + qq0) - qq0;
    }
    q_out[(size_t)row * EDIM + t] = v0;

    if (!do_qpk) return;

    {
        float s = v0, q0 = v0 * v0;
#pragma unroll
        for (int m = 1; m < 64; m <<= 1) {
            s += __shfl_xor(s, m); q0 += __shfl_xor(q0, m);
        }
        if (lane == 0) { red[wave][0] = s; red[wave][1] = q0; }
    }
    __syncthreads();
    {
        const float S0 = red[0][0] + red[1][0] + red[2][0] + red[3][0];
        const float Q0 = red[0][1] + red[1][1] + red[2][1] + red[3][1];
        const float m0 = S0 * (1.0f / EDIM);
        const float r0 = rsqrtf(Q0 * (1.0f / EDIM) - m0 * m0 + EPS_LN);
        qn[t] = (v0 - m0) * r0 * g_q[t] + b_q[t];
    }
    __syncthreads();
    float p0 = 0.f;
#pragma unroll 4
    for (int j = 0; j < EDIM; j += 4) {
        const float4 x0 = *reinterpret_cast<const float4*>(&qn[j]);
        p0 += x0.x * W[(size_t)j * EDIM + t] + x0.y * W[(size_t)(j + 1) * EDIM + t]
            + x0.z * W[(size_t)(j + 2) * EDIM + t] + x0.w * W[(size_t)(j + 3) * EDIM + t];
    }
    qpk[(size_t)row * EDIM + t] = p0;
    {
        float u0 = p0 * g_kv[t], w0 = p0 * b_kv[t];
#pragma unroll
        for (int m = 1; m < 64; m <<= 1) {
            u0 += __shfl_xor(u0, m); w0 += __shfl_xor(w0, m);
        }
        __syncthreads();
        if (lane == 0) { red[wave][0] = u0; red[wave][1] = w0; }
        __syncthreads();
        if (t == 0) {
            const int b = row >> 4;
            const int sl = row & 15;
            gqbq[b * 32 + sl] = red[0][0] + red[1][0] + red[2][0] + red[3][0];
            gqbq[b * 32 + 16 + sl] = red[0][1] + red[1][1] + red[2][1] + red[3][1];
        }
    }
}

extern "C" void kernel_launch(void* const* d_in, const int* in_sizes, int n_in,
                              void* d_out, int out_size, void* d_ws, size_t ws_size,
                              hipStream_t stream) {
    const float* input = (const float*)d_in[0];
    const float* query = (const float*)d_in[1];
    const float* g_kv = (const float*)d_in[2];
    const float* b_kv = (const float*)d_in[3];
    const float* w_k = (const float*)d_in[4];
    const float* w_v = (const float*)d_in[5];
    const float* g_q = (const float*)d_in[6];
    const float* b_q = (const float*)d_in[7];
    const float* w_q = (const float*)d_in[8];
    const float* w_ih = (const float*)d_in[9];
    const float* w_hh = (const float*)d_in[10];
    const float* b_ih = (const float*)d_in[11];
    const float* b_hh = (const float*)d_in[12];
    const float* g_2 = (const float*)d_in[13];
    const float* b_2 = (const float*)d_in[14];
    const float* w_f1 = (const float*)d_in[15];
    const float* b_f1 = (const float*)d_in[16];
    const float* w_f2 = (const float*)d_in[17];
    const float* b_f2 = (const float*)d_in[18];

    float* ws = (float*)d_ws;
    float* W = ws;        ws += 65536;
    float* qpk = ws;      ws += 131072;
    float* gqbq = ws;     ws += 1024;
    float* psum = ws;     ws += 32768;
    float* q_ws = ws;     ws += 131072;
    float* ub = ws;       ws += 131072;
    float* slots = ws;    ws += 131072;
    float* Mw = ws;       ws += 196608;   // folded w_v@w_ih  [256][768]
    float* w_ihT = ws;    ws += 196608;
    float* w_hhT = ws;    ws += 196608;
    float* w_f1T = ws;    ws += 262144;
    float* w_f2T = ws;    ws += 262144;
    float* pacc = ws;     ws += (size_t)NB * BPB * NS * EDIM;   // 16 MB
    float* gig = pacc;                        // 512*1536 overlay (after k_ub)
    float* h1 = pacc + 786432;                // 512*1024 overlay

    float* out_q = (float*)d_out;
    float* out_attn = out_q + (size_t)NB * NS * EDIM;

    k_prep<<<256, 256, 0, stream>>>(w_q, w_k, W);
    k_tr_all<<<224, 256, 0, stream>>>(w_ih, w_hh, w_f1, w_f2,
                                      w_ihT, w_hhT, w_f1T, w_f2T);
    k_prepM<<<256, 256, 0, stream>>>(w_v, w_ihT, Mw);
    k_qproj<<<512, 256, 0, stream>>>(query, g_q, b_q, W, g_kv, b_kv, qpk, gqbq);

    const float* qprev[3] = {query, q_ws, q_ws};
    float* qdst[3] = {q_ws, q_ws, out_q};
    const int adj[3] = {0, 1, 0};

    for (int it = 0; it < 3; ++it) {
        const bool last = (it == 2);
        if (last)
            k_bigpass<true><<<NB * BPB, 256, 0, stream>>>(input, qpk, gqbq, g_kv, pacc, psum, out_attn);
        else
            k_bigpass<false><<<NB * BPB, 256, 0, stream>>>(input, qpk, gqbq, g_kv, pacc, psum, nullptr);
        k_ub<<<512, 256, 0, stream>>>(pacc, psum, g_kv, b_kv, ub);
        k_gates<<<1536, 256, 0, stream>>>(ub, qprev[it], Mw, w_hhT, b_ih, b_hh, gig);
        k_gruffn1<<<1024, 256, 0, stream>>>(gig, qprev[it], g_2, b_2, w_f1T, b_f1, slots, h1);
        k_ffn2qpk<<<512, 256, 0, stream>>>(h1, slots, w_f2T, b_f2, query, g_q, b_q, W,
                                           g_kv, b_kv, qdst[it], qpk, gqbq,
                                           adj[it], last ? 0 : 1);
    }
}

// Round 22
// 444.862 us; speedup vs baseline: 1.0944x; 1.0944x over previous
//
#include <hip/hip_runtime.h>
#include <math.h>

#define NB 32
#define HW 4096
#define NS 16
#define EDIM 256
#define FFND 1024
#define EPS_LN 1e-5f
#define EPS_ATTN 1e-5f
#define BPB 32            // sub-blocks per batch in bigpass
#define RPB 128           // rows per bigpass block (HW/BPB)
#define TROWS 16          // rows per barrier-tile

__device__ __forceinline__ float sigmoidf_(float x) { return 1.0f / (1.0f + __expf(-x)); }
__device__ __forceinline__ float gelu_(float x) {
    float x3 = x * x * x;
    return 0.5f * x * (1.0f + tanhf(0.7978845608028654f * (x + 0.044715f * x3)));
}

// Sum across the 16-lane DPP row via row_ror rotations — pure VALU pipe.
__device__ __forceinline__ float rsum16(float v) {
    int x;
    x = __builtin_amdgcn_update_dpp(0, __float_as_int(v), 0x128, 0xF, 0xF, true); // ror:8
    v += __int_as_float(x);
    x = __builtin_amdgcn_update_dpp(0, __float_as_int(v), 0x124, 0xF, 0xF, true); // ror:4
    v += __int_as_float(x);
    x = __builtin_amdgcn_update_dpp(0, __float_as_int(v), 0x122, 0xF, 0xF, true); // ror:2
    v += __int_as_float(x);
    x = __builtin_amdgcn_update_dpp(0, __float_as_int(v), 0x121, 0xF, 0xF, true); // ror:1
    v += __int_as_float(x);
    return v;
}
// Max across the 16-lane DPP row.
__device__ __forceinline__ float rmax16(float v) {
    int x;
    x = __builtin_amdgcn_update_dpp(0, __float_as_int(v), 0x128, 0xF, 0xF, true);
    v = fmaxf(v, __int_as_float(x));
    x = __builtin_amdgcn_update_dpp(0, __float_as_int(v), 0x124, 0xF, 0xF, true);
    v = fmaxf(v, __int_as_float(x));
    x = __builtin_amdgcn_update_dpp(0, __float_as_int(v), 0x122, 0xF, 0xF, true);
    v = fmaxf(v, __int_as_float(x));
    x = __builtin_amdgcn_update_dpp(0, __float_as_int(v), 0x121, 0xF, 0xF, true);
    v = fmaxf(v, __int_as_float(x));
    return v;
}

// W[j][c] = scale * sum_e w_q[e][j] * w_k[e][c]   (scale = 256^-0.5 = 1/16)
__global__ void k_prep(const float* __restrict__ w_q, const float* __restrict__ w_k,
                       float* __restrict__ W) {
    const int j = blockIdx.x;
    const int c = threadIdx.x;
    float acc = 0.f;
    for (int e = 0; e < EDIM; ++e)
        acc += w_q[e * EDIM + j] * w_k[e * EDIM + c];
    W[j * EDIM + c] = acc * 0.0625f;
}

// Tiled transpose: src[R][C] -> dst[C][R].  R,C multiples of 64. 64x64 tiles.
__global__ __launch_bounds__(256) void k_tr(const float* __restrict__ src,
                                            float* __restrict__ dst, int R, int C) {
    __shared__ float tile[64][65];
    const int tilesC = C >> 6;
    const int tR = (blockIdx.x / tilesC) << 6;
    const int tC = (blockIdx.x % tilesC) << 6;
    const int t = threadIdx.x;
    {
        const int r = t >> 2;
        const int c0 = (t & 3) << 4;
#pragma unroll
        for (int i = 0; i < 16; i += 4) {
            const float4 v = *reinterpret_cast<const float4*>(src + (size_t)(tR + r) * C + tC + c0 + i);
            tile[r][c0 + i] = v.x; tile[r][c0 + i + 1] = v.y;
            tile[r][c0 + i + 2] = v.z; tile[r][c0 + i + 3] = v.w;
        }
    }
    __syncthreads();
    {
        const int c = t >> 2;
        const int r0 = (t & 3) << 4;
#pragma unroll
        for (int i = 0; i < 16; ++i)
            dst[(size_t)(tC + c) * R + tR + r0 + i] = tile[r0 + i][c];
    }
}

// Iteration-0 only: qn = LN(query_row); qpk = qn @ W; gq/bq scalars.
__global__ void k_qproj(const float* __restrict__ qsrc, const float* __restrict__ g_q,
                        const float* __restrict__ b_q, const float* __restrict__ W,
                        const float* __restrict__ g_kv, const float* __restrict__ b_kv,
                        float* __restrict__ qpk, float* __restrict__ gqbq) {
    const int row = blockIdx.x;   // 0..511  (= b*16 + s)
    const int t = threadIdx.x;
    __shared__ float qn[EDIM];
    __shared__ float red[16];
    const float v = qsrc[(size_t)row * EDIM + t];
    float s = v, ss = v * v;
#pragma unroll
    for (int m = 1; m < 64; m <<= 1) { s += __shfl_xor(s, m); ss += __shfl_xor(ss, m); }
    const int wave = t >> 6, lane = t & 63;
    if (lane == 0) { red[wave] = s; red[8 + wave] = ss; }
    __syncthreads();
    const float st = red[0] + red[1] + red[2] + red[3];
    const float sst = red[8] + red[9] + red[10] + red[11];
    const float mean = st * (1.0f / EDIM);
    const float rstd = rsqrtf(sst * (1.0f / EDIM) - mean * mean + EPS_LN);
    qn[t] = (v - mean) * rstd * g_q[t] + b_q[t];
    __syncthreads();
    float acc = 0.f;
    for (int j = 0; j < EDIM; ++j)
        acc += qn[j] * W[j * EDIM + t];
    qpk[(size_t)row * EDIM + t] = acc;
    float u = acc * g_kv[t];
    float w2 = acc * b_kv[t];
#pragma unroll
    for (int m = 1; m < 64; m <<= 1) { u += __shfl_xor(u, m); w2 += __shfl_xor(w2, m); }
    __syncthreads();
    if (lane == 0) { red[wave] = u; red[8 + wave] = w2; }
    __syncthreads();
    if (t == 0) {
        const int b = row >> 4, sl = row & 15;
        gqbq[b * 32 + sl] = red[0] + red[1] + red[2] + red[3];
        gqbq[b * 32 + 16 + sl] = red[8] + red[9] + red[10] + red[11];
    }
}

// Streaming pass v10 (proven 84us): G in regs, slot-split dot, DPP reductions,
// TROWS=16, register prefetch of next tile.
template <bool LAST>
__global__ __launch_bounds__(256, 2) void k_bigpass(
    const float* __restrict__ input, const float* __restrict__ qpk,
    const float* __restrict__ gqbq, const float* __restrict__ g_kv,
    float* __restrict__ pacc, float* __restrict__ psum, float* __restrict__ attn_out) {
    const int b = blockIdx.x >> 5;        // /BPB
    const int sub = blockIdx.x & 31;      // %BPB
    const int t = threadIdx.x;
    const int w = t >> 6;
    const int lane = t & 63;
    const int gp = (t >> 4) & 3;
    const int g = t >> 4;
    const int j = t & 15;

    __shared__ __align__(16) float stage[TROWS][264];
    __shared__ __align__(16) float wrec[TROWS][20];
    __shared__ __align__(16) float logit_lds[TROWS][NS];

    const float gqj = gqbq[b * 32 + j];
    const float bqj = gqbq[b * 32 + 16 + j];

    float4 Greg[4][4];
#pragma unroll
    for (int sp = 0; sp < 4; ++sp) {
#pragma unroll
        for (int c = 0; c < 4; ++c) {
            const int off = (c * 16 + j) * 4;
            const float4 qv = *reinterpret_cast<const float4*>(
                qpk + (size_t)b * 4096 + (w * 4 + sp) * 256 + off);
            const float4 gv = *reinterpret_cast<const float4*>(g_kv + off);
            Greg[sp][c] = make_float4(qv.x * gv.x, qv.y * gv.y, qv.z * gv.z, qv.w * gv.w);
        }
    }

    float acc[4][4];
    float S[4], A[4];
#pragma unroll
    for (int si = 0; si < 4; ++si) {
        acc[si][0] = acc[si][1] = acc[si][2] = acc[si][3] = 0.f;
        S[si] = 0.f; A[si] = 0.f;
    }

    const int rowbase = sub * RPB;

    float4 xh[4];
    {
        const float* xa = input + ((size_t)b * HW + rowbase + g) * EDIM;
#pragma unroll
        for (int c = 0; c < 4; ++c)
            xh[c] = *reinterpret_cast<const float4*>(xa + (c * 16 + j) * 4);
    }

#pragma unroll 1
    for (int tt = 0; tt < RPB / TROWS; ++tt) {
        const int grow = rowbase + tt * TROWS + g;

        float s1 = 0.f, s2 = 0.f;
#pragma unroll
        for (int c = 0; c < 4; ++c) {
            const int off = (c * 16 + j) * 4;
            *reinterpret_cast<float4*>(&stage[g][off]) = xh[c];
            s1 += xh[c].x + xh[c].y + xh[c].z + xh[c].w;
            s2 += xh[c].x * xh[c].x + xh[c].y * xh[c].y + xh[c].z * xh[c].z + xh[c].w * xh[c].w;
        }
        s1 = rsum16(s1);
        s2 = rsum16(s2);
        const float mean = s1 * (1.0f / EDIM);
        const float rstd = rsqrtf(s2 * (1.0f / EDIM) - mean * mean + EPS_LN);
        __syncthreads();

        if (tt + 1 < RPB / TROWS) {
            const float* xn = input + ((size_t)b * HW + rowbase + (tt + 1) * TROWS + g) * EDIM;
#pragma unroll
            for (int c = 0; c < 4; ++c)
                xh[c] = *reinterpret_cast<const float4*>(xn + (c * 16 + j) * 4);
        }

#pragma unroll
        for (int rb = 0; rb < 4; ++rb) {
            const int row = rb * 4 + gp;
            float d0 = 0.f, d1 = 0.f, d2 = 0.f, d3 = 0.f;
#pragma unroll
            for (int c = 0; c < 4; ++c) {
                const int off = (c * 16 + j) * 4;
                const float4 x = *reinterpret_cast<const float4*>(&stage[row][off]);
                d0 += x.x * Greg[0][c].x + x.y * Greg[0][c].y + x.z * Greg[0][c].z + x.w * Greg[0][c].w;
                d1 += x.x * Greg[1][c].x + x.y * Greg[1][c].y + x.z * Greg[1][c].z + x.w * Greg[1][c].w;
                d2 += x.x * Greg[2][c].x + x.y * Greg[2][c].y + x.z * Greg[2][c].z + x.w * Greg[2][c].w;
                d3 += x.x * Greg[3][c].x + x.y * Greg[3][c].y + x.z * Greg[3][c].z + x.w * Greg[3][c].w;
            }
            d0 = rsum16(d0); d1 = rsum16(d1); d2 = rsum16(d2); d3 = rsum16(d3);
            if (j == 0)
                *reinterpret_cast<float4*>(&logit_lds[row][w * 4]) =
                    make_float4(d0, d1, d2, d3);
        }
        __syncthreads();

        {
            float L = logit_lds[g][j];
            L = rstd * (L - mean * gqj) + bqj;
            const float mx = rmax16(L);
            const float p = __expf(L - mx);
            const float tot = rsum16(p);
            const float at = p / tot;
            wrec[g][j] = at;
            if (j == 0) {
                wrec[g][16] = rstd;
                wrec[g][17] = rstd * mean;
            }
            if (LAST)
                attn_out[((size_t)(b * NS + j)) * HW + grow] = at;
        }
        __syncthreads();

        {
            const int ch = lane * 4;
            const int sbase = w * 4;
#pragma unroll
            for (int r = 0; r < TROWS; ++r) {
                const float4 xv = *reinterpret_cast<const float4*>(&stage[r][ch]);
                const float4 at = *reinterpret_cast<const float4*>(&wrec[r][sbase]);
                const float rr = wrec[r][16];
                const float rm = wrec[r][17];
                float wg;
                wg = at.x * rr;
                acc[0][0] += wg * xv.x; acc[0][1] += wg * xv.y;
                acc[0][2] += wg * xv.z; acc[0][3] += wg * xv.w;
                S[0] += at.x; A[0] += at.x * rm;
                wg = at.y * rr;
                acc[1][0] += wg * xv.x; acc[1][1] += wg * xv.y;
                acc[1][2] += wg * xv.z; acc[1][3] += wg * xv.w;
                S[1] += at.y; A[1] += at.y * rm;
                wg = at.z * rr;
                acc[2][0] += wg * xv.x; acc[2][1] += wg * xv.y;
                acc[2][2] += wg * xv.z; acc[2][3] += wg * xv.w;
                S[2] += at.z; A[2] += at.z * rm;
                wg = at.w * rr;
                acc[3][0] += wg * xv.x; acc[3][1] += wg * xv.y;
                acc[3][2] += wg * xv.z; acc[3][3] += wg * xv.w;
                S[3] += at.w; A[3] += at.w * rm;
            }
        }
        __syncthreads();
    }

#pragma unroll
    for (int si = 0; si < 4; ++si) {
        *reinterpret_cast<float4*>(
            pacc + ((size_t)blockIdx.x * NS + w * 4 + si) * EDIM + lane * 4) =
            make_float4(acc[si][0], acc[si][1], acc[si][2], acc[si][3]);
    }
    if (lane == 0) {
#pragma unroll
        for (int si = 0; si < 4; ++si) {
            psum[blockIdx.x * 32 + w * 4 + si] = S[si];
            psum[blockIdx.x * 32 + 16 + w * 4 + si] = A[si];
        }
    }
}

// G1 v2: 2 rows/block (grid 512): partial reduce + ub + ub @ w_v.T.
__global__ __launch_bounds__(256) void k_upd(
    const float* __restrict__ pacc, const float* __restrict__ psum,
    const float* __restrict__ g_kv, const float* __restrict__ b_kv,
    const float* __restrict__ w_vT, float* __restrict__ updates) {
    const int rt = blockIdx.x >> 1;
    const int ct = blockIdx.x & 1;
    const int row0 = rt * 2;
    const int b = row0 >> 4;
    const int s0 = row0 & 15;
    const int t = threadIdx.x;
    __shared__ __align__(16) float ub[2][EDIM];
    __shared__ float sSA[2][2];

    if (t < 4) {
        const int r = t & 1;
        const int isA = t >> 1;
        float v = 0.f;
        for (int p = 0; p < BPB; ++p)
            v += psum[(b * BPB + p) * 32 + isA * 16 + s0 + r];
        sSA[r][isA] = v;
    }
    float V[2];
#pragma unroll
    for (int r = 0; r < 2; ++r) {
        float acc = 0.f;
        for (int p = 0; p < BPB; ++p)
            acc += pacc[((size_t)(b * BPB + p) * NS + s0 + r) * EDIM + t];
        V[r] = acc;
    }
    __syncthreads();
#pragma unroll
    for (int r = 0; r < 2; ++r) {
        const float Sv = sSA[r][0], Av = sSA[r][1];
        ub[r][t] = (g_kv[t] * (V[r] - Av) + b_kv[t] * Sv) / (Sv + EPS_ATTN);
    }
    __syncthreads();

    const int c = ct * 128 + (t & 127);
    const int half = t >> 7;
    const float* u0 = ub[half];
    float a0 = 0.f;
#pragma unroll 4
    for (int j = 0; j < EDIM; j += 4) {
        const float4 x0 = *reinterpret_cast<const float4*>(u0 + j);
        a0 += x0.x * w_vT[(size_t)j * EDIM + c] + x0.y * w_vT[(size_t)(j + 1) * EDIM + c]
            + x0.z * w_vT[(size_t)(j + 2) * EDIM + c] + x0.w * w_vT[(size_t)(j + 3) * EDIM + c];
    }
    updates[(size_t)(row0 + half) * EDIM + c] = a0;
}

// G2a v2: 2 rows/block (grid 1536).
__global__ __launch_bounds__(256) void k_gates(
    const float* __restrict__ updates, const float* __restrict__ qprev,
    const float* __restrict__ w_ihT, const float* __restrict__ w_hhT,
    const float* __restrict__ b_ih, const float* __restrict__ b_hh,
    float* __restrict__ gig) {
    const int rt = blockIdx.x / 6;
    const int ct = blockIdx.x % 6;
    const int row0 = rt * 2;
    const int t = threadIdx.x;
    const bool ih = ct < 3;
    const int lc = (ih ? ct : ct - 3) * 256 + t;
    const float* __restrict__ src = ih ? updates : qprev;
    const float* __restrict__ wT = ih ? w_ihT : w_hhT;

    __shared__ __align__(16) float in2[2][EDIM];
#pragma unroll
    for (int r = 0; r < 2; ++r)
        in2[r][t] = src[(size_t)(row0 + r) * EDIM + t];
    __syncthreads();

    float a0 = 0.f, a1 = 0.f;
#pragma unroll 4
    for (int j = 0; j < EDIM; j += 4) {
        const float4 x0 = *reinterpret_cast<const float4*>(&in2[0][j]);
        const float4 x1 = *reinterpret_cast<const float4*>(&in2[1][j]);
        const float w0 = wT[(size_t)j * 768 + lc];
        const float w1 = wT[(size_t)(j + 1) * 768 + lc];
        const float w2 = wT[(size_t)(j + 2) * 768 + lc];
        const float w3 = wT[(size_t)(j + 3) * 768 + lc];
        a0 += x0.x * w0 + x0.y * w1 + x0.z * w2 + x0.w * w3;
        a1 += x1.x * w0 + x1.y * w1 + x1.z * w2 + x1.w * w3;
    }
    const float bias = ih ? b_ih[lc] : b_hh[lc];
    const int gcol = ih ? lc : 768 + lc;
    gig[(size_t)(row0 + 0) * 1536 + gcol] = a0 + bias;
    gig[(size_t)(row0 + 1) * 1536 + gcol] = a1 + bias;
}

// G2b+G3 v2: 2 rows/block (grid 1024): GRU + LN + ffn1 slice.
__global__ __launch_bounds__(256) void k_gruffn1(
    const float* __restrict__ gig, const float* __restrict__ qprev,
    const float* __restrict__ g_2, const float* __restrict__ b_2,
    const float* __restrict__ w_f1T, const float* __restrict__ b_f1,
    float* __restrict__ slots, float* __restrict__ h1) {
    const int rt = blockIdx.x >> 2;
    const int ct = blockIdx.x & 3;
    const int row0 = rt * 2;
    const int t = threadIdx.x;
    const int wave = t >> 6, lane = t & 63;
    __shared__ __align__(16) float ln2[2][EDIM];
    __shared__ float red[4][4];

    float sl[2];
#pragma unroll
    for (int r = 0; r < 2; ++r) {
        const size_t base = (size_t)(row0 + r) * 1536;
        const float ir = gig[base + t];
        const float iz = gig[base + 256 + t];
        const float inn = gig[base + 512 + t];
        const float hr = gig[base + 768 + t];
        const float hz = gig[base + 1024 + t];
        const float hn = gig[base + 1280 + t];
        const float h = qprev[(size_t)(row0 + r) * EDIM + t];
        const float rg = sigmoidf_(ir + hr);
        const float z = sigmoidf_(iz + hz);
        const float n = tanhf(inn + rg * hn);
        sl[r] = (1.0f - z) * n + z * h;
    }
    if (ct == 0) {
#pragma unroll
        for (int r = 0; r < 2; ++r)
            slots[(size_t)(row0 + r) * EDIM + t] = sl[r];
    }
    {
        float a[2], qq[2];
#pragma unroll
        for (int r = 0; r < 2; ++r) { a[r] = sl[r]; qq[r] = sl[r] * sl[r]; }
#pragma unroll
        for (int m = 1; m < 64; m <<= 1) {
#pragma unroll
            for (int r = 0; r < 2; ++r) {
                a[r] += __shfl_xor(a[r], m);
                qq[r] += __shfl_xor(qq[r], m);
            }
        }
        if (lane == 0) {
#pragma unroll
            for (int r = 0; r < 2; ++r) { red[wave][r] = a[r]; red[wave][2 + r] = qq[r]; }
        }
    }
    __syncthreads();
    {
        const float g = g_2[t], bb = b_2[t];
#pragma unroll
        for (int r = 0; r < 2; ++r) {
            const float Sv = red[0][r] + red[1][r] + red[2][r] + red[3][r];
            const float Qv = red[0][2 + r] + red[1][2 + r] + red[2][2 + r] + red[3][2 + r];
            const float mn = Sv * (1.0f / EDIM);
            const float rs = rsqrtf(Qv * (1.0f / EDIM) - mn * mn + EPS_LN);
            ln2[r][t] = (sl[r] - mn) * rs * g + bb;
        }
    }
    __syncthreads();

    const int c = ct * 256 + t;
    float a0 = 0.f, a1 = 0.f;
#pragma unroll 4
    for (int j = 0; j < EDIM; j += 4) {
        const float4 x0 = *reinterpret_cast<const float4*>(&ln2[0][j]);
        const float4 x1 = *reinterpret_cast<const float4*>(&ln2[1][j]);
        const float w0 = w_f1T[(size_t)j * FFND + c];
        const float w1 = w_f1T[(size_t)(j + 1) * FFND + c];
        const float w2 = w_f1T[(size_t)(j + 2) * FFND + c];
        const float w3 = w_f1T[(size_t)(j + 3) * FFND + c];
        a0 += x0.x * w0 + x0.y * w1 + x0.z * w2 + x0.w * w3;
        a1 += x1.x * w0 + x1.y * w1 + x1.z * w2 + x1.w * w3;
    }
    const float bf = b_f1[c];
    h1[(size_t)(row0 + 0) * FFND + c] = gelu_(a0 + bf);
    h1[(size_t)(row0 + 1) * FFND + c] = gelu_(a1 + bf);
}

// G4+G5 v2: 1 row/block (grid 512).
__global__ __launch_bounds__(256) void k_ffn2qpk(
    const float* __restrict__ h1, const float* __restrict__ slots,
    const float* __restrict__ w_f2T, const float* __restrict__ b_f2,
    const float* __restrict__ query,
    const float* __restrict__ g_q, const float* __restrict__ b_q,
    const float* __restrict__ W,
    const float* __restrict__ g_kv, const float* __restrict__ b_kv,
    float* __restrict__ q_out, float* __restrict__ qpk, float* __restrict__ gqbq,
    int adjust, int do_qpk) {
    const int row = blockIdx.x;
    const int t = threadIdx.x;
    const int wave = t >> 6, lane = t & 63;
    __shared__ __align__(16) float in1[FFND];
    __shared__ float red[4][2];
    __shared__ __align__(16) float qn[EDIM];

    *reinterpret_cast<float4*>(&in1[t * 4]) =
        *reinterpret_cast<const float4*>(h1 + (size_t)row * FFND + t * 4);
    __syncthreads();
    float a0 = 0.f;
#pragma unroll 4
    for (int j = 0; j < FFND; j += 4) {
        const float4 x0 = *reinterpret_cast<const float4*>(&in1[j]);
        a0 += x0.x * w_f2T[(size_t)j * EDIM + t] + x0.y * w_f2T[(size_t)(j + 1) * EDIM + t]
            + x0.z * w_f2T[(size_t)(j + 2) * EDIM + t] + x0.w * w_f2T[(size_t)(j + 3) * EDIM + t];
    }
    float v0 = slots[(size_t)row * EDIM + t] + a0 + b_f2[t];
    if (adjust) {
        const float qq0 = query[(size_t)row * EDIM + t];
        v0 = (v0 + qq0) - qq0;
    }
    q_out[(size_t)row * EDIM + t] = v0;

    if (!do_qpk) return;

    {
        float s = v0, q0 = v0 * v0;
#pragma unroll
        for (int m = 1; m < 64; m <<= 1) {
            s += __shfl_xor(s, m); q0 += __shfl_xor(q0, m);
        }
        if (lane == 0) { red[wave][0] = s; red[wave][1] = q0; }
    }
    __syncthreads();
    {
        const float S0 = red[0][0] + red[1][0] + red[2][0] + red[3][0];
        const float Q0 = red[0][1] + red[1][1] + red[2][1] + red[3][1];
        const float m0 = S0 * (1.0f / EDIM);
        const float r0 = rsqrtf(Q0 * (1.0f / EDIM) - m0 * m0 + EPS_LN);
        qn[t] = (v0 - m0) * r0 * g_q[t] + b_q[t];
    }
    __syncthreads();
    float p0 = 0.f;
#pragma unroll 4
    for (int j = 0; j < EDIM; j += 4) {
        const float4 x0 = *reinterpret_cast<const float4*>(&qn[j]);
        p0 += x0.x * W[(size_t)j * EDIM + t] + x0.y * W[(size_t)(j + 1) * EDIM + t]
            + x0.z * W[(size_t)(j + 2) * EDIM + t] + x0.w * W[(size_t)(j + 3) * EDIM + t];
    }
    qpk[(size_t)row * EDIM + t] = p0;
    {
        float u0 = p0 * g_kv[t], w0 = p0 * b_kv[t];
#pragma unroll
        for (int m = 1; m < 64; m <<= 1) {
            u0 += __shfl_xor(u0, m); w0 += __shfl_xor(w0, m);
        }
        __syncthreads();
        if (lane == 0) { red[wave][0] = u0; red[wave][1] = w0; }
        __syncthreads();
        if (t == 0) {
            const int b = row >> 4;
            const int sl = row & 15;
            gqbq[b * 32 + sl] = red[0][0] + red[1][0] + red[2][0] + red[3][0];
            gqbq[b * 32 + 16 + sl] = red[0][1] + red[1][1] + red[2][1] + red[3][1];
        }
    }
}

extern "C" void kernel_launch(void* const* d_in, const int* in_sizes, int n_in,
                              void* d_out, int out_size, void* d_ws, size_t ws_size,
                              hipStream_t stream) {
    const float* input = (const float*)d_in[0];
    const float* query = (const float*)d_in[1];
    const float* g_kv = (const float*)d_in[2];
    const float* b_kv = (const float*)d_in[3];
    const float* w_k = (const float*)d_in[4];
    const float* w_v = (const float*)d_in[5];
    const float* g_q = (const float*)d_in[6];
    const float* b_q = (const float*)d_in[7];
    const float* w_q = (const float*)d_in[8];
    const float* w_ih = (const float*)d_in[9];
    const float* w_hh = (const float*)d_in[10];
    const float* b_ih = (const float*)d_in[11];
    const float* b_hh = (const float*)d_in[12];
    const float* g_2 = (const float*)d_in[13];
    const float* b_2 = (const float*)d_in[14];
    const float* w_f1 = (const float*)d_in[15];
    const float* b_f1 = (const float*)d_in[16];
    const float* w_f2 = (const float*)d_in[17];
    const float* b_f2 = (const float*)d_in[18];

    float* ws = (float*)d_ws;
    float* W = ws;        ws += 65536;
    float* qpk = ws;      ws += 131072;
    float* gqbq = ws;     ws += 1024;
    float* psum = ws;     ws += 32768;
    float* q_ws = ws;     ws += 131072;
    float* updates = ws;  ws += 131072;
    float* slots = ws;    ws += 131072;
    float* w_vT = ws;     ws += 65536;
    float* w_ihT = ws;    ws += 196608;
    float* w_hhT = ws;    ws += 196608;
    float* w_f1T = ws;    ws += 262144;
    float* w_f2T = ws;    ws += 262144;
    float* pacc = ws;     ws += (size_t)NB * BPB * NS * EDIM;   // 16 MB
    float* gig = pacc;                        // 512*1536 overlay (after k_upd)
    float* h1 = pacc + 786432;                // 512*1024 overlay

    float* out_q = (float*)d_out;
    float* out_attn = out_q + (size_t)NB * NS * EDIM;

    k_prep<<<256, 256, 0, stream>>>(w_q, w_k, W);
    k_tr<<<16, 256, 0, stream>>>(w_v, w_vT, 256, 256);
    k_tr<<<48, 256, 0, stream>>>(w_ih, w_ihT, 768, 256);
    k_tr<<<48, 256, 0, stream>>>(w_hh, w_hhT, 768, 256);
    k_tr<<<64, 256, 0, stream>>>(w_f1, w_f1T, 1024, 256);
    k_tr<<<64, 256, 0, stream>>>(w_f2, w_f2T, 256, 1024);
    k_qproj<<<512, 256, 0, stream>>>(query, g_q, b_q, W, g_kv, b_kv, qpk, gqbq);

    const float* qprev[3] = {query, q_ws, q_ws};
    float* qdst[3] = {q_ws, q_ws, out_q};
    const int adj[3] = {0, 1, 0};

    for (int it = 0; it < 3; ++it) {
        const bool last = (it == 2);
        if (last)
            k_bigpass<true><<<NB * BPB, 256, 0, stream>>>(input, qpk, gqbq, g_kv, pacc, psum, out_attn);
        else
            k_bigpass<false><<<NB * BPB, 256, 0, stream>>>(input, qpk, gqbq, g_kv, pacc, psum, nullptr);
        k_upd<<<512, 256, 0, stream>>>(pacc, psum, g_kv, b_kv, w_vT, updates);
        k_gates<<<1536, 256, 0, stream>>>(updates, qprev[it], w_ihT, w_hhT, b_ih, b_hh, gig);
        k_gruffn1<<<1024, 256, 0, stream>>>(gig, qprev[it], g_2, b_2, w_f1T, b_f1, slots, h1);
        k_ffn2qpk<<<512, 256, 0, stream>>>(h1, slots, w_f2T, b_f2, query, g_q, b_q, W,
                                           g_kv, b_kv, qdst[it], qpk, gqbq,
                                           adj[it], last ? 0 : 1);
    }
}